// Round 10
// baseline (224.877 us; speedup 1.0000x reference)
//
#include <hip/hip_runtime.h>
#include <hip/hip_bf16.h>

#define S_LEN 4096
#define DMODEL 512
#define NHEAD 8
#define HDIM 64

typedef __bf16 bf16x8 __attribute__((ext_vector_type(8)));
typedef __bf16 bf16x4 __attribute__((ext_vector_type(4)));
typedef float f32x4 __attribute__((ext_vector_type(4)));

#define S2EXP 0.18033688011112042f   // 0.125 * log2(e), folded into Q projection

__device__ __forceinline__ void gload_lds16(const void* g, void* l) {
    __builtin_amdgcn_global_load_lds((const __attribute__((address_space(1))) void*)g,
                                     (__attribute__((address_space(3))) void*)l, 16, 0, 0);
}

// ---------------- fused prologue ----------------
// bid <  512 : q+k projection (MFMA); q output pre-scaled by S2EXP
// bid < 1024 : v projection (MFMA) + transpose to vt[h][d][s]
// bid < 3072 : mask bit-packing
// bid < 3104 : Wfc f32->bf16
__global__ __launch_bounds__(256) void pre_kernel(const float* __restrict__ xq,
                                                  const float* __restrict__ xk,
                                                  const float* __restrict__ xv,
                                                  const float* __restrict__ Wq,
                                                  const float* __restrict__ bq,
                                                  const float* __restrict__ Wk,
                                                  const float* __restrict__ bk,
                                                  const float* __restrict__ Wv,
                                                  const float* __restrict__ bv,
                                                  __bf16* __restrict__ yq,
                                                  __bf16* __restrict__ yk,
                                                  __bf16* __restrict__ vt,
                                                  const int* __restrict__ mask,
                                                  unsigned int* __restrict__ pack,
                                                  const float* __restrict__ Wfc,
                                                  __bf16* __restrict__ wfc_bf) {
    __shared__ float T[64][65];
    int bid = blockIdx.x;
    int t = threadIdx.x, wave = t >> 6, lane = t & 63, lg = lane >> 4, lc = lane & 15;
    if (bid < 512) {
        int r0 = bid * 64 + wave * 16;
        const float* xrq = xq + (size_t)(r0 + lc) * 64 + lg * 8;
        const float* xrk = xk + (size_t)(r0 + lc) * 64 + lg * 8;
        bf16x8 aq[2], ak[2];
#pragma unroll
        for (int c = 0; c < 2; ++c) {
            f32x4 u0 = *(const f32x4*)(xrq + c * 32);
            f32x4 u1 = *(const f32x4*)(xrq + c * 32 + 4);
            f32x4 v0 = *(const f32x4*)(xrk + c * 32);
            f32x4 v1 = *(const f32x4*)(xrk + c * 32 + 4);
            bf16x8 a, b;
#pragma unroll
            for (int j = 0; j < 4; ++j) {
                a[j] = (__bf16)u0[j]; a[4 + j] = (__bf16)u1[j];
                b[j] = (__bf16)v0[j]; b[4 + j] = (__bf16)v1[j];
            }
            aq[c] = a; ak[c] = b;
        }
#pragma unroll
        for (int nt = 0; nt < 4; ++nt) {
            const float* wq = Wq + (size_t)(nt * 16 + lc) * 64 + lg * 8;
            const float* wk = Wk + (size_t)(nt * 16 + lc) * 64 + lg * 8;
            f32x4 cq = {0, 0, 0, 0}, ck = {0, 0, 0, 0};
#pragma unroll
            for (int c = 0; c < 2; ++c) {
                f32x4 u0 = *(const f32x4*)(wq + c * 32);
                f32x4 u1 = *(const f32x4*)(wq + c * 32 + 4);
                f32x4 v0 = *(const f32x4*)(wk + c * 32);
                f32x4 v1 = *(const f32x4*)(wk + c * 32 + 4);
                bf16x8 bw, bw2;
#pragma unroll
                for (int j = 0; j < 4; ++j) {
                    bw[j] = (__bf16)u0[j]; bw[4 + j] = (__bf16)u1[j];
                    bw2[j] = (__bf16)v0[j]; bw2[4 + j] = (__bf16)v1[j];
                }
                cq = __builtin_amdgcn_mfma_f32_16x16x32_bf16(aq[c], bw, cq, 0, 0, 0);
                ck = __builtin_amdgcn_mfma_f32_16x16x32_bf16(ak[c], bw2, ck, 0, 0, 0);
            }
            float bqv = bq[nt * 16 + lc], bkv = bk[nt * 16 + lc];
#pragma unroll
            for (int r = 0; r < 4; ++r) {
                yq[(size_t)(r0 + lg * 4 + r) * 64 + nt * 16 + lc] = (__bf16)((cq[r] + bqv) * S2EXP);
                yk[(size_t)(r0 + lg * 4 + r) * 64 + nt * 16 + lc] = (__bf16)(ck[r] + bkv);
            }
        }
    } else if (bid < 1024) {
        int vb = bid - 512;
        int h = vb & 7, s0 = (vb >> 3) * 64;
        const float* xr = xv + ((size_t)(s0 + wave * 16 + lc) * 8 + h) * 64 + lg * 8;
        bf16x8 av[2];
#pragma unroll
        for (int c = 0; c < 2; ++c) {
            f32x4 u0 = *(const f32x4*)(xr + c * 32);
            f32x4 u1 = *(const f32x4*)(xr + c * 32 + 4);
            bf16x8 a;
#pragma unroll
            for (int j = 0; j < 4; ++j) { a[j] = (__bf16)u0[j]; a[4 + j] = (__bf16)u1[j]; }
            av[c] = a;
        }
#pragma unroll
        for (int nt = 0; nt < 4; ++nt) {
            const float* wv = Wv + (size_t)(nt * 16 + lc) * 64 + lg * 8;
            f32x4 cv = {0, 0, 0, 0};
#pragma unroll
            for (int c = 0; c < 2; ++c) {
                f32x4 u0 = *(const f32x4*)(wv + c * 32);
                f32x4 u1 = *(const f32x4*)(wv + c * 32 + 4);
                bf16x8 bw;
#pragma unroll
                for (int j = 0; j < 4; ++j) { bw[j] = (__bf16)u0[j]; bw[4 + j] = (__bf16)u1[j]; }
                cv = __builtin_amdgcn_mfma_f32_16x16x32_bf16(av[c], bw, cv, 0, 0, 0);
            }
            float bvv = bv[nt * 16 + lc];
#pragma unroll
            for (int r = 0; r < 4; ++r) T[wave * 16 + lg * 4 + r][nt * 16 + lc] = cv[r] + bvv;
        }
        __syncthreads();
        int d = t >> 2, qr = t & 3;
        bf16x8 w0, w1;
#pragma unroll
        for (int i = 0; i < 8; ++i) {
            w0[i] = (__bf16)T[qr * 16 + i][d];
            w1[i] = (__bf16)T[qr * 16 + 8 + i][d];
        }
        __bf16* dst = vt + ((size_t)h * 64 + d) * 4096 + s0 + qr * 16;
        *(bf16x8*)(dst) = w0;
        *(bf16x8*)(dst + 8) = w1;
    } else if (bid < 3072) {
        int wid = (bid - 1024) * 4 + (t >> 6);
#pragma unroll 4
        for (int it = 0; it < 32; ++it) {
            int gw = wid * 32 + it;
            int qi = gw >> 6, seg = gw & 63;
            unsigned long long bits = __ballot(mask[(size_t)qi * 4096 + seg * 64 + lane] != 0);
            if (lane == 0)
                *(unsigned long long*)(&pack[(size_t)qi * 128 + seg * 2]) = bits;
        }
    } else {
        int b = bid - 3072;
        const f32x4* s4 = (const f32x4*)Wfc;
#pragma unroll
        for (int i = 0; i < 8; ++i) {
            int idx = (b * 8 + i) * 256 + t;
            f32x4 v = s4[idx];
            bf16x4 o;
#pragma unroll
            for (int j = 0; j < 4; ++j) o[j] = (__bf16)v[j];
            *(bf16x4*)(wfc_bf + (size_t)idx * 4) = o;
        }
    }
}

// ---------------- flash attention: KV-step 32, K via LDS, V direct from L2 ----------------
// block: h = bid&7 (head -> XCD, keeps K/V L2-resident), qt = (bid>>3)&63, sp = bid>>9
__global__ __launch_bounds__(256, 6) void attn_kernel(const __bf16* __restrict__ qb,
                                                      const __bf16* __restrict__ kb,
                                                      const __bf16* __restrict__ vt,
                                                      const unsigned int* __restrict__ mp,
                                                      int split_steps,
                                                      float* __restrict__ opart,
                                                      float* __restrict__ stats,
                                                      __bf16* __restrict__ ao) {
    int bid = blockIdx.x;
    int h = bid & 7, qt = (bid >> 3) & 63, sp = bid >> 9;
    int kv0 = sp * split_steps * 32;
    int nsteps = min(split_steps, 128 - sp * split_steps);
    int t = threadIdx.x, wave = t >> 6, lane = t & 63, lg = lane >> 4, lc = lane & 15;
    int q0 = qt * 64 + wave * 16;

    __shared__ __bf16 Kt[2][32 * 64];    // 4KB/buf: k-rows, 128B, XOR swz ((row&7)<<4)
    __shared__ __bf16 P[4][16 * 32];     // 1KB/wave: q-rows, 64B, chunk-rotation swz

    int srK = lane >> 3;
    int cgK = (lane & 7) ^ srK;                      // inverse XOR swizzle (K)

    const __bf16* qrow = qb + ((size_t)(q0 + lc) * 8 + h) * 64 + lg * 8;
    bf16x8 qf0 = *(const bf16x8*)(qrow);
    bf16x8 qf1 = *(const bf16x8*)(qrow + 32);

    bf16x8 onesf;
#pragma unroll
    for (int j = 0; j < 8; ++j) onesf[j] = (__bf16)1.0f;

    f32x4 o0 = {0,0,0,0}, o1 = {0,0,0,0}, o2 = {0,0,0,0}, o3 = {0,0,0,0};
    f32x4 l_acc = {0,0,0,0};

    const unsigned int* mrow = mp + (size_t)(q0 + lc) * 128;
    const __bf16* vbase = vt + (size_t)h * 64 * 4096;

    // V direct-read pointers (L2-resident; advance by 32 elems per step)
    const __bf16* vp0 = vbase + (size_t)(0 * 16 + lc) * 4096 + kv0 + lg * 8;
    const __bf16* vp1 = vbase + (size_t)(1 * 16 + lc) * 4096 + kv0 + lg * 8;
    const __bf16* vp2 = vbase + (size_t)(2 * 16 + lc) * 4096 + kv0 + lg * 8;
    const __bf16* vp3 = vbase + (size_t)(3 * 16 + lc) * 4096 + kv0 + lg * 8;

    // ---- stage K tile 0 (wave w stages instr w) ----
    gload_lds16(kb + (size_t)(kv0 + wave * 8 + srK) * 512 + h * 64 + cgK * 8, &Kt[0][wave * 512]);
    __syncthreads();

    int rotP = (lc >> 1) & 3;
    int lg4 = lg * 4;
    for (int step = 0; step < nsteps; ++step) {
        int cur = step & 1;
        int kb_i = kv0 + step * 32;
        if (step < nsteps - 1) {
            int nxt = kb_i + 32;
            gload_lds16(kb + (size_t)(nxt + wave * 8 + srK) * 512 + h * 64 + cgK * 8, &Kt[cur ^ 1][wave * 512]);
        }
        // ---- V fragments direct from L2 (independent of QK^T -> latency hides) ----
        bf16x8 vf0 = *(const bf16x8*)(vp0);
        bf16x8 vf1 = *(const bf16x8*)(vp1);
        bf16x8 vf2 = *(const bf16x8*)(vp2);
        bf16x8 vf3 = *(const bf16x8*)(vp3);
        vp0 += 32; vp1 += 32; vp2 += 32; vp3 += 32;
        // ---- QK^T swapped (Q pre-scaled): sc = score*0.125*log2e ----
        const char* Kb = (const char*)&Kt[cur][0];
        f32x4 sc[2];
#pragma unroll
        for (int kc = 0; kc < 2; ++kc) {
            int row = kc * 16 + lc;
            int sw = (row & 7) << 4;
            bf16x8 kf0 = *(const bf16x8*)(Kb + ((row * 128 + lg * 16) ^ sw));
            bf16x8 kf1 = *(const bf16x8*)(Kb + ((row * 128 + 64 + lg * 16) ^ sw));
            f32x4 z = {0,0,0,0};
            z = __builtin_amdgcn_mfma_f32_16x16x32_bf16(kf0, qf0, z, 0, 0, 0);
            z = __builtin_amdgcn_mfma_f32_16x16x32_bf16(kf1, qf1, z, 0, 0, 0);
            sc[kc] = z;
        }
        // ---- p = exp2(sc), masked to 0 via bfe_i32 sign-extract + AND ----
        unsigned int mws = mrow[kb_i >> 5] >> lg4;   // hoisted per-lane shift
        char* pbase = (char*)&P[wave][0];
#pragma unroll
        for (int kc = 0; kc < 2; ++kc) {
            bf16x4 pk;
#pragma unroll
            for (int r = 0; r < 4; ++r) {
                float p = __builtin_amdgcn_exp2f(sc[kc][r]);
                int sel = __builtin_amdgcn_sbfe((int)mws, kc * 16 + r, 1);  // 0 or -1
                pk[r] = (__bf16)__int_as_float(__float_as_int(p) & sel);
            }
            int phys = ((kc * 2 + (lg >> 1)) + rotP) & 3;
            int byte = lc * 64 + phys * 16 + (lg & 1) * 8;
            *(bf16x4*)(pbase + byte) = pk;
        }
        // ---- PV (+ l row-sum via ones-B MFMA): single K=32 chunk ----
        bf16x8 pf = *(const bf16x8*)(pbase + (lc * 64 + (((lg + rotP) & 3) * 16)));
        l_acc = __builtin_amdgcn_mfma_f32_16x16x32_bf16(pf, onesf, l_acc, 0, 0, 0);
        o0 = __builtin_amdgcn_mfma_f32_16x16x32_bf16(pf, vf0, o0, 0, 0, 0);
        o1 = __builtin_amdgcn_mfma_f32_16x16x32_bf16(pf, vf1, o1, 0, 0, 0);
        o2 = __builtin_amdgcn_mfma_f32_16x16x32_bf16(pf, vf2, o2, 0, 0, 0);
        o3 = __builtin_amdgcn_mfma_f32_16x16x32_bf16(pf, vf3, o3, 0, 0, 0);
        __syncthreads();
    }
    if (opart) {
        if (lc == 0) {
#pragma unroll
            for (int r = 0; r < 4; ++r)
                stats[(size_t)sp * 32768 + (size_t)(q0 + lg * 4 + r) * 8 + h] = l_acc[r];
        }
#pragma unroll
        for (int r = 0; r < 4; ++r) {
            size_t rh = (size_t)sp * 32768 + (size_t)(q0 + lg * 4 + r) * 8 + h;
            float* dst = opart + rh * 64;
            dst[0 * 16 + lc] = o0[r];
            dst[1 * 16 + lc] = o1[r];
            dst[2 * 16 + lc] = o2[r];
            dst[3 * 16 + lc] = o3[r];
        }
    } else {
#pragma unroll
        for (int r = 0; r < 4; ++r) {
            float inv = 1.0f / l_acc[r];
            int row = q0 + lg * 4 + r;
            __bf16* dst = ao + (size_t)row * 512 + h * 64;
            dst[0 * 16 + lc] = (__bf16)(o0[r] * inv);
            dst[1 * 16 + lc] = (__bf16)(o1[r] * inv);
            dst[2 * 16 + lc] = (__bf16)(o2[r] * inv);
            dst[3 * 16 + lc] = (__bf16)(o3[r] * inv);
        }
    }
}

// ---------------- split-KV combine (no-max softmax: plain sums) ----------------
__global__ __launch_bounds__(256) void combine_kernel(const float* __restrict__ opart,
                                                      const float* __restrict__ stats,
                                                      __bf16* __restrict__ ao, int nsplit) {
    int t = threadIdx.x, lane = t & 63, w = t >> 6;
    int rh = blockIdx.x * 4 + w;     // row*8 + h
    float L = 0.f, acc = 0.f;
#pragma unroll 4
    for (int sp = 0; sp < nsplit; ++sp) {
        L += stats[(size_t)sp * 32768 + rh];
        acc += opart[((size_t)sp * 32768 + rh) * 64 + lane];
    }
    int row = rh >> 3, h = rh & 7;
    ao[(size_t)row * 512 + h * 64 + lane] = (__bf16)(acc / L);
}

// ---------------- final FC: out[s][n] = sum_k ao[s][k] * Wfc[n][k] + bfc[n] ----------------
__global__ __launch_bounds__(256) void fc_kernel(const __bf16* __restrict__ ao,
                                                 const __bf16* __restrict__ Wb,
                                                 const float* __restrict__ bfc,
                                                 float* __restrict__ out) {
    int bid = blockIdx.x;
    int stile = bid >> 3, nt = bid & 7;
    int t = threadIdx.x, wave = t >> 6, lane = t & 63, lg = lane >> 4, lc = lane & 15;
    int s0 = stile * 64 + wave * 16;
    int n0 = nt * 64;
    f32x4 c0 = {0,0,0,0}, c1 = {0,0,0,0}, c2 = {0,0,0,0}, c3 = {0,0,0,0};
    for (int k0 = 0; k0 < 512; k0 += 32) {
        bf16x8 af = *(const bf16x8*)(ao + (size_t)(s0 + lc) * 512 + k0 + lg * 8);
        const __bf16* wb = Wb + k0 + lg * 8;
        c0 = __builtin_amdgcn_mfma_f32_16x16x32_bf16(af, *(const bf16x8*)(wb + (size_t)(n0 + 0 * 16 + lc) * 512), c0, 0, 0, 0);
        c1 = __builtin_amdgcn_mfma_f32_16x16x32_bf16(af, *(const bf16x8*)(wb + (size_t)(n0 + 1 * 16 + lc) * 512), c1, 0, 0, 0);
        c2 = __builtin_amdgcn_mfma_f32_16x16x32_bf16(af, *(const bf16x8*)(wb + (size_t)(n0 + 2 * 16 + lc) * 512), c2, 0, 0, 0);
        c3 = __builtin_amdgcn_mfma_f32_16x16x32_bf16(af, *(const bf16x8*)(wb + (size_t)(n0 + 3 * 16 + lc) * 512), c3, 0, 0, 0);
    }
#pragma unroll
    for (int r = 0; r < 4; ++r) {
        int row = s0 + lg * 4 + r;
        float* dst = out + (size_t)row * 512 + n0;
        dst[0 * 16 + lc] = c0[r] + bfc[n0 + 0 * 16 + lc];
        dst[1 * 16 + lc] = c1[r] + bfc[n0 + 1 * 16 + lc];
        dst[2 * 16 + lc] = c2[r] + bfc[n0 + 2 * 16 + lc];
        dst[3 * 16 + lc] = c3[r] + bfc[n0 + 3 * 16 + lc];
    }
}

extern "C" void kernel_launch(void* const* d_in, const int* in_sizes, int n_in,
                              void* d_out, int out_size, void* d_ws, size_t ws_size,
                              hipStream_t stream) {
    const float* query = (const float*)d_in[0];
    const float* key   = (const float*)d_in[1];
    const float* value = (const float*)d_in[2];
    const int*   mask  = (const int*)d_in[3];
    const float* Wq  = (const float*)d_in[4];
    const float* bq  = (const float*)d_in[5];
    const float* Wk  = (const float*)d_in[6];
    const float* bk  = (const float*)d_in[7];
    const float* Wv  = (const float*)d_in[8];
    const float* bv  = (const float*)d_in[9];
    const float* Wfc = (const float*)d_in[10];
    const float* bfc = (const float*)d_in[11];

    char* ws = (char*)d_ws;
    const size_t MB = 1024 * 1024;
    __bf16* q_bf   = (__bf16*)(ws + 0 * MB);      // 4 MB  [S*H][64]
    __bf16* k_bf   = (__bf16*)(ws + 4 * MB);      // 4 MB  [S*H][64]
    __bf16* vt     = (__bf16*)(ws + 8 * MB);      // 4 MB  [H][64][S]
    __bf16* ao     = (__bf16*)(ws + 12 * MB);     // 4 MB  [S][512]
    __bf16* wfc_bf = (__bf16*)(ws + 16 * MB);     // 0.5 MB
    unsigned int* mpack = (unsigned int*)(ws + 17 * MB);  // 2 MB [S][128]
    const size_t base = 19 * MB;
    int nsplit = 1, split_steps = 128;
    if (ws_size >= base + 3 * (8 * MB) + 3 * 131072)      { nsplit = 3; split_steps = 43; }
    else if (ws_size >= base + 2 * (8 * MB) + 2 * 131072) { nsplit = 2; split_steps = 64; }
    float* opart = (float*)(ws + base);
    float* stats = (float*)(ws + base + (size_t)nsplit * 8 * MB);

    pre_kernel<<<3104, 256, 0, stream>>>(query, key, value, Wq, bq, Wk, bk, Wv, bv,
                                         q_bf, k_bf, vt, mask, mpack, Wfc, wfc_bf);
    if (nsplit > 1) {
        attn_kernel<<<512 * nsplit, 256, 0, stream>>>(q_bf, k_bf, vt, mpack,
                                                      split_steps, opart, stats, ao);
        combine_kernel<<<8192, 256, 0, stream>>>(opart, stats, ao, nsplit);
    } else {
        attn_kernel<<<512, 256, 0, stream>>>(q_bf, k_bf, vt, mpack,
                                             split_steps, nullptr, nullptr, ao);
    }
    fc_kernel<<<512, 256, 0, stream>>>(ao, wfc_bf, bfc, (float*)d_out);
}

// Round 11
// 135.066 us; speedup vs baseline: 1.6649x; 1.6649x over previous
//
#include <hip/hip_runtime.h>
#include <hip/hip_bf16.h>

#define S_LEN 4096
#define DMODEL 512
#define NHEAD 8
#define HDIM 64

typedef __bf16 bf16x8 __attribute__((ext_vector_type(8)));
typedef __bf16 bf16x4 __attribute__((ext_vector_type(4)));
typedef float f32x4 __attribute__((ext_vector_type(4)));

#define S2EXP 0.18033688011112042f   // 0.125 * log2(e), folded into Q projection

__device__ __forceinline__ void gload_lds16(const void* g, void* l) {
    __builtin_amdgcn_global_load_lds((const __attribute__((address_space(1))) void*)g,
                                     (__attribute__((address_space(3))) void*)l, 16, 0, 0);
}

// ---------------- fused projections: blocks 0-511 q+k, 512-1023 v(+transpose) ----------------
__global__ __launch_bounds__(256) void proj_all_kernel(const float* __restrict__ xq,
                                                       const float* __restrict__ xk,
                                                       const float* __restrict__ xv,
                                                       const float* __restrict__ Wq,
                                                       const float* __restrict__ bq,
                                                       const float* __restrict__ Wk,
                                                       const float* __restrict__ bk,
                                                       const float* __restrict__ Wv,
                                                       const float* __restrict__ bv,
                                                       __bf16* __restrict__ yq,
                                                       __bf16* __restrict__ yk,
                                                       __bf16* __restrict__ vt) {
    __shared__ float T[64][65];
    int bid = blockIdx.x;
    int t = threadIdx.x, wave = t >> 6, lane = t & 63, lg = lane >> 4, lc = lane & 15;
    if (bid < 512) {
        int r0 = bid * 64 + wave * 16;
        const float* xrq = xq + (size_t)(r0 + lc) * 64 + lg * 8;
        const float* xrk = xk + (size_t)(r0 + lc) * 64 + lg * 8;
        bf16x8 aq[2], ak[2];
#pragma unroll
        for (int c = 0; c < 2; ++c) {
            f32x4 u0 = *(const f32x4*)(xrq + c * 32);
            f32x4 u1 = *(const f32x4*)(xrq + c * 32 + 4);
            f32x4 v0 = *(const f32x4*)(xrk + c * 32);
            f32x4 v1 = *(const f32x4*)(xrk + c * 32 + 4);
            bf16x8 a, b;
#pragma unroll
            for (int j = 0; j < 4; ++j) {
                a[j] = (__bf16)u0[j]; a[4 + j] = (__bf16)u1[j];
                b[j] = (__bf16)v0[j]; b[4 + j] = (__bf16)v1[j];
            }
            aq[c] = a; ak[c] = b;
        }
#pragma unroll
        for (int nt = 0; nt < 4; ++nt) {
            const float* wq = Wq + (size_t)(nt * 16 + lc) * 64 + lg * 8;
            const float* wk = Wk + (size_t)(nt * 16 + lc) * 64 + lg * 8;
            f32x4 cq = {0, 0, 0, 0}, ck = {0, 0, 0, 0};
#pragma unroll
            for (int c = 0; c < 2; ++c) {
                f32x4 u0 = *(const f32x4*)(wq + c * 32);
                f32x4 u1 = *(const f32x4*)(wq + c * 32 + 4);
                f32x4 v0 = *(const f32x4*)(wk + c * 32);
                f32x4 v1 = *(const f32x4*)(wk + c * 32 + 4);
                bf16x8 bw, bw2;
#pragma unroll
                for (int j = 0; j < 4; ++j) {
                    bw[j] = (__bf16)u0[j]; bw[4 + j] = (__bf16)u1[j];
                    bw2[j] = (__bf16)v0[j]; bw2[4 + j] = (__bf16)v1[j];
                }
                cq = __builtin_amdgcn_mfma_f32_16x16x32_bf16(aq[c], bw, cq, 0, 0, 0);
                ck = __builtin_amdgcn_mfma_f32_16x16x32_bf16(ak[c], bw2, ck, 0, 0, 0);
            }
            float bqv = bq[nt * 16 + lc], bkv = bk[nt * 16 + lc];
#pragma unroll
            for (int r = 0; r < 4; ++r) {
                yq[(size_t)(r0 + lg * 4 + r) * 64 + nt * 16 + lc] = (__bf16)((cq[r] + bqv) * S2EXP);
                yk[(size_t)(r0 + lg * 4 + r) * 64 + nt * 16 + lc] = (__bf16)(ck[r] + bkv);
            }
        }
    } else {
        int vb = bid - 512;
        int h = vb & 7, s0 = (vb >> 3) * 64;
        const float* xr = xv + ((size_t)(s0 + wave * 16 + lc) * 8 + h) * 64 + lg * 8;
        bf16x8 av[2];
#pragma unroll
        for (int c = 0; c < 2; ++c) {
            f32x4 u0 = *(const f32x4*)(xr + c * 32);
            f32x4 u1 = *(const f32x4*)(xr + c * 32 + 4);
            bf16x8 a;
#pragma unroll
            for (int j = 0; j < 4; ++j) { a[j] = (__bf16)u0[j]; a[4 + j] = (__bf16)u1[j]; }
            av[c] = a;
        }
#pragma unroll
        for (int nt = 0; nt < 4; ++nt) {
            const float* wv = Wv + (size_t)(nt * 16 + lc) * 64 + lg * 8;
            f32x4 cv = {0, 0, 0, 0};
#pragma unroll
            for (int c = 0; c < 2; ++c) {
                f32x4 u0 = *(const f32x4*)(wv + c * 32);
                f32x4 u1 = *(const f32x4*)(wv + c * 32 + 4);
                bf16x8 bw;
#pragma unroll
                for (int j = 0; j < 4; ++j) { bw[j] = (__bf16)u0[j]; bw[4 + j] = (__bf16)u1[j]; }
                cv = __builtin_amdgcn_mfma_f32_16x16x32_bf16(av[c], bw, cv, 0, 0, 0);
            }
            float bvv = bv[nt * 16 + lc];
#pragma unroll
            for (int r = 0; r < 4; ++r) T[wave * 16 + lg * 4 + r][nt * 16 + lc] = cv[r] + bvv;
        }
        __syncthreads();
        int d = t >> 2, qr = t & 3;
        bf16x8 w0, w1;
#pragma unroll
        for (int i = 0; i < 8; ++i) {
            w0[i] = (__bf16)T[qr * 16 + i][d];
            w1[i] = (__bf16)T[qr * 16 + 8 + i][d];
        }
        __bf16* dst = vt + ((size_t)h * 64 + d) * 4096 + s0 + qr * 16;
        *(bf16x8*)(dst) = w0;
        *(bf16x8*)(dst + 8) = w1;
    }
}

// ---------------- prep: blocks 0-2047 mask packing, 2048-2079 Wfc f32->bf16 ----------------
__global__ __launch_bounds__(256) void prep_kernel(const int* __restrict__ mask,
                                                   unsigned int* __restrict__ pack,
                                                   const float* __restrict__ Wfc,
                                                   __bf16* __restrict__ wfc_bf) {
    int bid = blockIdx.x;
    int t = threadIdx.x;
    if (bid < 2048) {
        int lane = t & 63;
        int wid = bid * 4 + (t >> 6);
#pragma unroll 4
        for (int it = 0; it < 32; ++it) {
            int gw = wid * 32 + it;
            int qi = gw >> 6, seg = gw & 63;
            unsigned long long bits = __ballot(mask[(size_t)qi * 4096 + seg * 64 + lane] != 0);
            if (lane == 0)
                *(unsigned long long*)(&pack[(size_t)qi * 128 + seg * 2]) = bits;
        }
    } else {
        int b = bid - 2048;
        const f32x4* s4 = (const f32x4*)Wfc;
#pragma unroll
        for (int i = 0; i < 8; ++i) {
            int idx = (b * 8 + i) * 256 + t;     // f32x4 index, 65536 total
            f32x4 v = s4[idx];
            bf16x4 o;
#pragma unroll
            for (int j = 0; j < 4; ++j) o[j] = (__bf16)v[j];
            *(bf16x4*)(wfc_bf + (size_t)idx * 4) = o;
        }
    }
}

// ---------------- flash attention: R8 body, 8 blocks/CU ----------------
// block: h = bid&7 (head -> XCD), qt = (bid>>3)&63, sp = bid>>9
__global__ __launch_bounds__(256, 8) void attn_kernel(const __bf16* __restrict__ qb,
                                                      const __bf16* __restrict__ kb,
                                                      const __bf16* __restrict__ vt,
                                                      const unsigned int* __restrict__ mp,
                                                      int split_steps,
                                                      float* __restrict__ opart,
                                                      float* __restrict__ stats,
                                                      __bf16* __restrict__ ao) {
    int bid = blockIdx.x;
    int h = bid & 7, qt = (bid >> 3) & 63, sp = bid >> 9;
    int kv0 = sp * split_steps * 32;
    int nsteps = min(split_steps, 128 - sp * split_steps);
    int t = threadIdx.x, wave = t >> 6, lane = t & 63, lg = lane >> 4, lc = lane & 15;
    int q0 = qt * 64 + wave * 16;

    __shared__ __bf16 Kt[2][32 * 64];    // 4KB/buf: k-rows, 128B, XOR swz ((row&7)<<4)
    __shared__ __bf16 Vt[2][64 * 32];    // 4KB/buf: d-rows, 64B, chunk-rotation swz
    __shared__ __bf16 P[4][16 * 32];     // 1KB/wave: q-rows, 64B, chunk-rotation swz

    int srK = lane >> 3;
    int cgK = (lane & 7) ^ srK;                      // inverse XOR swizzle (K)
    int srV = lane >> 2;
    int cgV = ((lane & 3) - ((lane >> 3) & 3)) & 3;  // inverse rotation (V)

    const __bf16* qrow = qb + ((size_t)(q0 + lc) * 8 + h) * 64 + lg * 8;
    bf16x8 qf0 = *(const bf16x8*)(qrow);
    bf16x8 qf1 = *(const bf16x8*)(qrow + 32);

    bf16x8 onesf;
#pragma unroll
    for (int j = 0; j < 8; ++j) onesf[j] = (__bf16)1.0f;

    f32x4 o0 = {0,0,0,0}, o1 = {0,0,0,0}, o2 = {0,0,0,0}, o3 = {0,0,0,0};
    f32x4 l_acc = {0,0,0,0};

    const unsigned int* mrow = mp + (size_t)(q0 + lc) * 128;
    const __bf16* vbase = vt + (size_t)h * 64 * 4096;

    // ---- stage tile 0 ----
    gload_lds16(kb + (size_t)(kv0 + wave * 8 + srK) * 512 + h * 64 + cgK * 8, &Kt[0][wave * 512]);
    gload_lds16(vbase + (size_t)(wave * 16 + srV) * 4096 + kv0 + cgV * 8,     &Vt[0][wave * 512]);
    __syncthreads();

    int rotP = (lc >> 1) & 3;
    int lg4 = lg * 4;
    for (int step = 0; step < nsteps; ++step) {
        int cur = step & 1;
        int kb_i = kv0 + step * 32;
        if (step < nsteps - 1) {
            int nxt = kb_i + 32;
            gload_lds16(kb + (size_t)(nxt + wave * 8 + srK) * 512 + h * 64 + cgK * 8, &Kt[cur ^ 1][wave * 512]);
            gload_lds16(vbase + (size_t)(wave * 16 + srV) * 4096 + nxt + cgV * 8,     &Vt[cur ^ 1][wave * 512]);
        }
        // ---- QK^T swapped (Q pre-scaled): sc = score*0.125*log2e ----
        const char* Kb = (const char*)&Kt[cur][0];
        f32x4 sc[2];
#pragma unroll
        for (int kc = 0; kc < 2; ++kc) {
            int row = kc * 16 + lc;
            int sw = (row & 7) << 4;
            bf16x8 kf0 = *(const bf16x8*)(Kb + ((row * 128 + lg * 16) ^ sw));
            bf16x8 kf1 = *(const bf16x8*)(Kb + ((row * 128 + 64 + lg * 16) ^ sw));
            f32x4 z = {0,0,0,0};
            z = __builtin_amdgcn_mfma_f32_16x16x32_bf16(kf0, qf0, z, 0, 0, 0);
            z = __builtin_amdgcn_mfma_f32_16x16x32_bf16(kf1, qf1, z, 0, 0, 0);
            sc[kc] = z;
        }
        // ---- p = exp2(sc), masked to 0 via bfe_i32 sign-extract + AND ----
        unsigned int mws = mrow[kb_i >> 5] >> lg4;   // hoisted per-lane shift
        char* pbase = (char*)&P[wave][0];
#pragma unroll
        for (int kc = 0; kc < 2; ++kc) {
            bf16x4 pk;
#pragma unroll
            for (int r = 0; r < 4; ++r) {
                float p = __builtin_amdgcn_exp2f(sc[kc][r]);
                int sel = __builtin_amdgcn_sbfe((int)mws, kc * 16 + r, 1);  // 0 or -1
                pk[r] = (__bf16)__int_as_float(__float_as_int(p) & sel);
            }
            int phys = ((kc * 2 + (lg >> 1)) + rotP) & 3;
            int byte = lc * 64 + phys * 16 + (lg & 1) * 8;
            *(bf16x4*)(pbase + byte) = pk;
        }
        // ---- PV (+ l row-sum via ones-B MFMA): single K=32 chunk ----
        const char* Vb = (const char*)&Vt[cur][0];
        bf16x8 pf = *(const bf16x8*)(pbase + (lc * 64 + (((lg + rotP) & 3) * 16)));
        l_acc = __builtin_amdgcn_mfma_f32_16x16x32_bf16(pf, onesf, l_acc, 0, 0, 0);
#pragma unroll
        for (int dt = 0; dt < 4; ++dt) {
            int row = dt * 16 + lc;
            bf16x8 vf = *(const bf16x8*)(Vb + (row * 64 + (((lg + rotP) & 3) * 16)));
            if (dt == 0) o0 = __builtin_amdgcn_mfma_f32_16x16x32_bf16(pf, vf, o0, 0, 0, 0);
            if (dt == 1) o1 = __builtin_amdgcn_mfma_f32_16x16x32_bf16(pf, vf, o1, 0, 0, 0);
            if (dt == 2) o2 = __builtin_amdgcn_mfma_f32_16x16x32_bf16(pf, vf, o2, 0, 0, 0);
            if (dt == 3) o3 = __builtin_amdgcn_mfma_f32_16x16x32_bf16(pf, vf, o3, 0, 0, 0);
        }
        __syncthreads();
    }
    if (opart) {
        if (lc == 0) {
#pragma unroll
            for (int r = 0; r < 4; ++r)
                stats[(size_t)sp * 32768 + (size_t)(q0 + lg * 4 + r) * 8 + h] = l_acc[r];
        }
#pragma unroll
        for (int r = 0; r < 4; ++r) {
            size_t rh = (size_t)sp * 32768 + (size_t)(q0 + lg * 4 + r) * 8 + h;
            float* dst = opart + rh * 64;
            dst[0 * 16 + lc] = o0[r];
            dst[1 * 16 + lc] = o1[r];
            dst[2 * 16 + lc] = o2[r];
            dst[3 * 16 + lc] = o3[r];
        }
    } else {
#pragma unroll
        for (int r = 0; r < 4; ++r) {
            float inv = 1.0f / l_acc[r];
            int row = q0 + lg * 4 + r;
            __bf16* dst = ao + (size_t)row * 512 + h * 64;
            dst[0 * 16 + lc] = (__bf16)(o0[r] * inv);
            dst[1 * 16 + lc] = (__bf16)(o1[r] * inv);
            dst[2 * 16 + lc] = (__bf16)(o2[r] * inv);
            dst[3 * 16 + lc] = (__bf16)(o3[r] * inv);
        }
    }
}

// ---------------- split-KV combine (no-max softmax: plain sums) ----------------
__global__ __launch_bounds__(256) void combine_kernel(const float* __restrict__ opart,
                                                      const float* __restrict__ stats,
                                                      __bf16* __restrict__ ao, int nsplit) {
    int t = threadIdx.x, lane = t & 63, w = t >> 6;
    int rh = blockIdx.x * 4 + w;     // row*8 + h
    float L = 0.f, acc = 0.f;
#pragma unroll 4
    for (int sp = 0; sp < nsplit; ++sp) {
        L += stats[(size_t)sp * 32768 + rh];
        acc += opart[((size_t)sp * 32768 + rh) * 64 + lane];
    }
    int row = rh >> 3, h = rh & 7;
    ao[(size_t)row * 512 + h * 64 + lane] = (__bf16)(acc / L);
}

// ---------------- final FC: out[s][n] = sum_k ao[s][k] * Wfc[n][k] + bfc[n] ----------------
__global__ __launch_bounds__(256) void fc_kernel(const __bf16* __restrict__ ao,
                                                 const __bf16* __restrict__ Wb,
                                                 const float* __restrict__ bfc,
                                                 float* __restrict__ out) {
    int bid = blockIdx.x;
    int stile = bid >> 3, nt = bid & 7;
    int t = threadIdx.x, wave = t >> 6, lane = t & 63, lg = lane >> 4, lc = lane & 15;
    int s0 = stile * 64 + wave * 16;
    int n0 = nt * 64;
    f32x4 c0 = {0,0,0,0}, c1 = {0,0,0,0}, c2 = {0,0,0,0}, c3 = {0,0,0,0};
    for (int k0 = 0; k0 < 512; k0 += 32) {
        bf16x8 af = *(const bf16x8*)(ao + (size_t)(s0 + lc) * 512 + k0 + lg * 8);
        const __bf16* wb = Wb + k0 + lg * 8;
        c0 = __builtin_amdgcn_mfma_f32_16x16x32_bf16(af, *(const bf16x8*)(wb + (size_t)(n0 + 0 * 16 + lc) * 512), c0, 0, 0, 0);
        c1 = __builtin_amdgcn_mfma_f32_16x16x32_bf16(af, *(const bf16x8*)(wb + (size_t)(n0 + 1 * 16 + lc) * 512), c1, 0, 0, 0);
        c2 = __builtin_amdgcn_mfma_f32_16x16x32_bf16(af, *(const bf16x8*)(wb + (size_t)(n0 + 2 * 16 + lc) * 512), c2, 0, 0, 0);
        c3 = __builtin_amdgcn_mfma_f32_16x16x32_bf16(af, *(const bf16x8*)(wb + (size_t)(n0 + 3 * 16 + lc) * 512), c3, 0, 0, 0);
    }
#pragma unroll
    for (int r = 0; r < 4; ++r) {
        int row = s0 + lg * 4 + r;
        float* dst = out + (size_t)row * 512 + n0;
        dst[0 * 16 + lc] = c0[r] + bfc[n0 + 0 * 16 + lc];
        dst[1 * 16 + lc] = c1[r] + bfc[n0 + 1 * 16 + lc];
        dst[2 * 16 + lc] = c2[r] + bfc[n0 + 2 * 16 + lc];
        dst[3 * 16 + lc] = c3[r] + bfc[n0 + 3 * 16 + lc];
    }
}

extern "C" void kernel_launch(void* const* d_in, const int* in_sizes, int n_in,
                              void* d_out, int out_size, void* d_ws, size_t ws_size,
                              hipStream_t stream) {
    const float* query = (const float*)d_in[0];
    const float* key   = (const float*)d_in[1];
    const float* value = (const float*)d_in[2];
    const int*   mask  = (const int*)d_in[3];
    const float* Wq  = (const float*)d_in[4];
    const float* bq  = (const float*)d_in[5];
    const float* Wk  = (const float*)d_in[6];
    const float* bk  = (const float*)d_in[7];
    const float* Wv  = (const float*)d_in[8];
    const float* bv  = (const float*)d_in[9];
    const float* Wfc = (const float*)d_in[10];
    const float* bfc = (const float*)d_in[11];

    char* ws = (char*)d_ws;
    const size_t MB = 1024 * 1024;
    __bf16* q_bf   = (__bf16*)(ws + 0 * MB);      // 4 MB  [S*H][64]
    __bf16* k_bf   = (__bf16*)(ws + 4 * MB);      // 4 MB  [S*H][64]
    __bf16* vt     = (__bf16*)(ws + 8 * MB);      // 4 MB  [H][64][S]
    __bf16* ao     = (__bf16*)(ws + 12 * MB);     // 4 MB  [S][512]
    __bf16* wfc_bf = (__bf16*)(ws + 16 * MB);     // 0.5 MB
    unsigned int* mpack = (unsigned int*)(ws + 17 * MB);  // 2 MB [S][128]
    const size_t base = 19 * MB;
    int nsplit = 1, split_steps = 128;
    if (ws_size >= base + 4 * (8 * MB) + 4 * 131072)      { nsplit = 4; split_steps = 32; }
    else if (ws_size >= base + 2 * (8 * MB) + 2 * 131072) { nsplit = 2; split_steps = 64; }
    float* opart = (float*)(ws + base);
    float* stats = (float*)(ws + base + (size_t)nsplit * 8 * MB);

    proj_all_kernel<<<1024, 256, 0, stream>>>(query, key, value, Wq, bq, Wk, bk, Wv, bv,
                                              q_bf, k_bf, vt);
    prep_kernel<<<2080, 256, 0, stream>>>(mask, mpack, Wfc, wfc_bf);
    if (nsplit > 1) {
        attn_kernel<<<512 * nsplit, 256, 0, stream>>>(q_bf, k_bf, vt, mpack,
                                                      split_steps, opart, stats, ao);
        combine_kernel<<<8192, 256, 0, stream>>>(opart, stats, ao, nsplit);
    } else {
        attn_kernel<<<512, 256, 0, stream>>>(q_bf, k_bf, vt, mpack,
                                             split_steps, nullptr, nullptr, ao);
    }
    fc_kernel<<<512, 256, 0, stream>>>(ao, wfc_bf, bfc, (float*)d_out);
}

// Round 12
// 123.576 us; speedup vs baseline: 1.8197x; 1.0930x over previous
//
#include <hip/hip_runtime.h>
#include <hip/hip_bf16.h>

#define S_LEN 4096
#define DMODEL 512
#define NHEAD 8
#define HDIM 64

typedef __bf16 bf16x8 __attribute__((ext_vector_type(8)));
typedef __bf16 bf16x4 __attribute__((ext_vector_type(4)));
typedef float f32x4 __attribute__((ext_vector_type(4)));

#define S2EXP 0.18033688011112042f   // 0.125 * log2(e), folded into Q projection

__device__ __forceinline__ void gload_lds16(const void* g, void* l) {
    __builtin_amdgcn_global_load_lds((const __attribute__((address_space(1))) void*)g,
                                     (__attribute__((address_space(3))) void*)l, 16, 0, 0);
}
__device__ __forceinline__ void gload_lds4(const void* g, void* l) {
    __builtin_amdgcn_global_load_lds((const __attribute__((address_space(1))) void*)g,
                                     (__attribute__((address_space(3))) void*)l, 4, 0, 0);
}

// ---------------- fused projections: blocks 0-511 q+k, 512-1023 v(+transpose) ----------------
__global__ __launch_bounds__(256) void proj_all_kernel(const float* __restrict__ xq,
                                                       const float* __restrict__ xk,
                                                       const float* __restrict__ xv,
                                                       const float* __restrict__ Wq,
                                                       const float* __restrict__ bq,
                                                       const float* __restrict__ Wk,
                                                       const float* __restrict__ bk,
                                                       const float* __restrict__ Wv,
                                                       const float* __restrict__ bv,
                                                       __bf16* __restrict__ yq,
                                                       __bf16* __restrict__ yk,
                                                       __bf16* __restrict__ vt) {
    __shared__ float T[64][65];
    int bid = blockIdx.x;
    int t = threadIdx.x, wave = t >> 6, lane = t & 63, lg = lane >> 4, lc = lane & 15;
    if (bid < 512) {
        int r0 = bid * 64 + wave * 16;
        const float* xrq = xq + (size_t)(r0 + lc) * 64 + lg * 8;
        const float* xrk = xk + (size_t)(r0 + lc) * 64 + lg * 8;
        bf16x8 aq[2], ak[2];
#pragma unroll
        for (int c = 0; c < 2; ++c) {
            f32x4 u0 = *(const f32x4*)(xrq + c * 32);
            f32x4 u1 = *(const f32x4*)(xrq + c * 32 + 4);
            f32x4 v0 = *(const f32x4*)(xrk + c * 32);
            f32x4 v1 = *(const f32x4*)(xrk + c * 32 + 4);
            bf16x8 a, b;
#pragma unroll
            for (int j = 0; j < 4; ++j) {
                a[j] = (__bf16)u0[j]; a[4 + j] = (__bf16)u1[j];
                b[j] = (__bf16)v0[j]; b[4 + j] = (__bf16)v1[j];
            }
            aq[c] = a; ak[c] = b;
        }
#pragma unroll
        for (int nt = 0; nt < 4; ++nt) {
            const float* wq = Wq + (size_t)(nt * 16 + lc) * 64 + lg * 8;
            const float* wk = Wk + (size_t)(nt * 16 + lc) * 64 + lg * 8;
            f32x4 cq = {0, 0, 0, 0}, ck = {0, 0, 0, 0};
#pragma unroll
            for (int c = 0; c < 2; ++c) {
                f32x4 u0 = *(const f32x4*)(wq + c * 32);
                f32x4 u1 = *(const f32x4*)(wq + c * 32 + 4);
                f32x4 v0 = *(const f32x4*)(wk + c * 32);
                f32x4 v1 = *(const f32x4*)(wk + c * 32 + 4);
                bf16x8 bw, bw2;
#pragma unroll
                for (int j = 0; j < 4; ++j) {
                    bw[j] = (__bf16)u0[j]; bw[4 + j] = (__bf16)u1[j];
                    bw2[j] = (__bf16)v0[j]; bw2[4 + j] = (__bf16)v1[j];
                }
                cq = __builtin_amdgcn_mfma_f32_16x16x32_bf16(aq[c], bw, cq, 0, 0, 0);
                ck = __builtin_amdgcn_mfma_f32_16x16x32_bf16(ak[c], bw2, ck, 0, 0, 0);
            }
            float bqv = bq[nt * 16 + lc], bkv = bk[nt * 16 + lc];
#pragma unroll
            for (int r = 0; r < 4; ++r) {
                yq[(size_t)(r0 + lg * 4 + r) * 64 + nt * 16 + lc] = (__bf16)((cq[r] + bqv) * S2EXP);
                yk[(size_t)(r0 + lg * 4 + r) * 64 + nt * 16 + lc] = (__bf16)(ck[r] + bkv);
            }
        }
    } else {
        int vb = bid - 512;
        int h = vb & 7, s0 = (vb >> 3) * 64;
        const float* xr = xv + ((size_t)(s0 + wave * 16 + lc) * 8 + h) * 64 + lg * 8;
        bf16x8 av[2];
#pragma unroll
        for (int c = 0; c < 2; ++c) {
            f32x4 u0 = *(const f32x4*)(xr + c * 32);
            f32x4 u1 = *(const f32x4*)(xr + c * 32 + 4);
            bf16x8 a;
#pragma unroll
            for (int j = 0; j < 4; ++j) { a[j] = (__bf16)u0[j]; a[4 + j] = (__bf16)u1[j]; }
            av[c] = a;
        }
#pragma unroll
        for (int nt = 0; nt < 4; ++nt) {
            const float* wv = Wv + (size_t)(nt * 16 + lc) * 64 + lg * 8;
            f32x4 cv = {0, 0, 0, 0};
#pragma unroll
            for (int c = 0; c < 2; ++c) {
                f32x4 u0 = *(const f32x4*)(wv + c * 32);
                f32x4 u1 = *(const f32x4*)(wv + c * 32 + 4);
                bf16x8 bw;
#pragma unroll
                for (int j = 0; j < 4; ++j) { bw[j] = (__bf16)u0[j]; bw[4 + j] = (__bf16)u1[j]; }
                cv = __builtin_amdgcn_mfma_f32_16x16x32_bf16(av[c], bw, cv, 0, 0, 0);
            }
            float bvv = bv[nt * 16 + lc];
#pragma unroll
            for (int r = 0; r < 4; ++r) T[wave * 16 + lg * 4 + r][nt * 16 + lc] = cv[r] + bvv;
        }
        __syncthreads();
        int d = t >> 2, qr = t & 3;
        bf16x8 w0, w1;
#pragma unroll
        for (int i = 0; i < 8; ++i) {
            w0[i] = (__bf16)T[qr * 16 + i][d];
            w1[i] = (__bf16)T[qr * 16 + 8 + i][d];
        }
        __bf16* dst = vt + ((size_t)h * 64 + d) * 4096 + s0 + qr * 16;
        *(bf16x8*)(dst) = w0;
        *(bf16x8*)(dst + 8) = w1;
    }
}

// ---------------- prep: blocks 0-2047 mask packing, 2048-2079 Wfc f32->bf16 ----------------
__global__ __launch_bounds__(256) void prep_kernel(const int* __restrict__ mask,
                                                   unsigned int* __restrict__ pack,
                                                   const float* __restrict__ Wfc,
                                                   __bf16* __restrict__ wfc_bf) {
    int bid = blockIdx.x;
    int t = threadIdx.x;
    if (bid < 2048) {
        int lane = t & 63;
        int wid = bid * 4 + (t >> 6);
#pragma unroll 4
        for (int it = 0; it < 32; ++it) {
            int gw = wid * 32 + it;
            int qi = gw >> 6, seg = gw & 63;
            unsigned long long bits = __ballot(mask[(size_t)qi * 4096 + seg * 64 + lane] != 0);
            if (lane == 0)
                *(unsigned long long*)(&pack[(size_t)qi * 128 + seg * 2]) = bits;
        }
    } else {
        int b = bid - 2048;
        const f32x4* s4 = (const f32x4*)Wfc;
#pragma unroll
        for (int i = 0; i < 8; ++i) {
            int idx = (b * 8 + i) * 256 + t;     // f32x4 index, 65536 total
            f32x4 v = s4[idx];
            bf16x4 o;
#pragma unroll
            for (int j = 0; j < 4; ++j) o[j] = (__bf16)v[j];
            *(bf16x4*)(wfc_bf + (size_t)idx * 4) = o;
        }
    }
}

// ---------------- flash attention: 4-buffer counted-vmcnt pipeline, KV-step 32 ----------------
// block: h = bid&7 (head -> XCD), qt = (bid>>3)&63, sp = bid>>9
// Per step s: stage tile s+2 -> vmcnt(4) (tile s landed; s+1,s+2 in flight) -> s_barrier -> compute.
// 4 LDS buffers: buffer overwritten at step s was consumed at step s-2; all waves passed
// barrier(s-1) => finished compute(s-2), so no race. Mask words staged by wave 0 so the
// compute phase contains NO global loads (nothing for the compiler to drain vmcnt on).
__global__ __launch_bounds__(256, 4) void attn_kernel(const __bf16* __restrict__ qb,
                                                      const __bf16* __restrict__ kb,
                                                      const __bf16* __restrict__ vt,
                                                      const unsigned int* __restrict__ mp,
                                                      int split_steps,
                                                      float* __restrict__ opart,
                                                      float* __restrict__ stats,
                                                      __bf16* __restrict__ ao) {
    int bid = blockIdx.x;
    int h = bid & 7, qt = (bid >> 3) & 63, sp = bid >> 9;
    int kv0 = sp * split_steps * 32;
    int nsteps = split_steps;            // split_steps divides 128 evenly (64 or 128)
    int t = threadIdx.x, wave = t >> 6, lane = t & 63, lg = lane >> 4, lc = lane & 15;
    int q0 = qt * 64 + wave * 16;

    __shared__ __bf16 Kt[4][32 * 64];        // 4 x 4KB: k-rows, 128B, XOR swz ((row&7)<<4)
    __shared__ __bf16 Vt[4][64 * 32];        // 4 x 4KB: d-rows, 64B, chunk-rotation swz
    __shared__ __bf16 P[4][16 * 32];         // 4KB: per-wave P tile
    __shared__ unsigned int Mld[4][64];      // 1KB: mask word per q-row per buffered tile

    int srK = lane >> 3;
    int cgK = (lane & 7) ^ srK;                      // inverse XOR swizzle (K)
    int srV = lane >> 2;
    int cgV = ((lane & 3) - ((lane >> 3) & 3)) & 3;  // inverse rotation (V)

    const __bf16* qrow = qb + ((size_t)(q0 + lc) * 8 + h) * 64 + lg * 8;
    bf16x8 qf0 = *(const bf16x8*)(qrow);
    bf16x8 qf1 = *(const bf16x8*)(qrow + 32);

    bf16x8 onesf;
#pragma unroll
    for (int j = 0; j < 8; ++j) onesf[j] = (__bf16)1.0f;

    f32x4 o0 = {0,0,0,0}, o1 = {0,0,0,0}, o2 = {0,0,0,0}, o3 = {0,0,0,0};
    f32x4 l_acc = {0,0,0,0};

    const __bf16* vbase = vt + (size_t)h * 64 * 4096;
    const unsigned int* mbase = mp + (size_t)(qt * 64 + lane) * 128 + (kv0 >> 5);

    int rotP = (lc >> 1) & 3;
    int lg4 = lg * 4;

    // ---- staging helper (tile index tt relative to kv0) ----
#define STAGE(tt, B)                                                                       \
    {                                                                                      \
        if (wave == 0) gload_lds4(mbase + (tt), &Mld[B][0]);                               \
        gload_lds16(kb + (size_t)(kv0 + (tt) * 32 + wave * 8 + srK) * 512 + h * 64 + cgK * 8, \
                    &Kt[B][wave * 512]);                                                   \
        gload_lds16(vbase + (size_t)(wave * 16 + srV) * 4096 + kv0 + (tt) * 32 + cgV * 8,  \
                    &Vt[B][wave * 512]);                                                   \
    }

    // ---- prologue: stage tiles 0,1; full drain once ----
    STAGE(0, 0)
    STAGE(1, 1)
    asm volatile("s_waitcnt vmcnt(0)" ::: "memory");
    __builtin_amdgcn_s_barrier();

#define ATTN_STEP(s, C, G)                                                                 \
    {                                                                                      \
        if ((s) + 2 < nsteps) STAGE((s) + 2, G)                                            \
        asm volatile("s_waitcnt vmcnt(4)" ::: "memory");                                   \
        __builtin_amdgcn_s_barrier();                                                      \
        unsigned int mws = Mld[C][wave * 16 + lc] >> lg4;                                  \
        const char* Kb = (const char*)&Kt[C][0];                                           \
        f32x4 sc0 = {0,0,0,0}, sc1 = {0,0,0,0};                                            \
        {                                                                                  \
            int row = lc, sw = (row & 7) << 4;                                             \
            bf16x8 kf0 = *(const bf16x8*)(Kb + ((row * 128 + lg * 16) ^ sw));              \
            bf16x8 kf1 = *(const bf16x8*)(Kb + ((row * 128 + 64 + lg * 16) ^ sw));         \
            sc0 = __builtin_amdgcn_mfma_f32_16x16x32_bf16(kf0, qf0, sc0, 0, 0, 0);         \
            sc0 = __builtin_amdgcn_mfma_f32_16x16x32_bf16(kf1, qf1, sc0, 0, 0, 0);         \
        }                                                                                  \
        {                                                                                  \
            int row = 16 + lc, sw = (row & 7) << 4;                                        \
            bf16x8 kf0 = *(const bf16x8*)(Kb + ((row * 128 + lg * 16) ^ sw));              \
            bf16x8 kf1 = *(const bf16x8*)(Kb + ((row * 128 + 64 + lg * 16) ^ sw));         \
            sc1 = __builtin_amdgcn_mfma_f32_16x16x32_bf16(kf0, qf0, sc1, 0, 0, 0);         \
            sc1 = __builtin_amdgcn_mfma_f32_16x16x32_bf16(kf1, qf1, sc1, 0, 0, 0);         \
        }                                                                                  \
        char* pbase = (char*)&P[wave][0];                                                  \
        {                                                                                  \
            bf16x4 pk0, pk1;                                                               \
            _Pragma("unroll")                                                              \
            for (int r = 0; r < 4; ++r) {                                                  \
                float pa = __builtin_amdgcn_exp2f(sc0[r]);                                 \
                int sa = __builtin_amdgcn_sbfe((int)mws, r, 1);                            \
                pk0[r] = (__bf16)__int_as_float(__float_as_int(pa) & sa);                  \
                float pb = __builtin_amdgcn_exp2f(sc1[r]);                                 \
                int sb = __builtin_amdgcn_sbfe((int)mws, 16 + r, 1);                       \
                pk1[r] = (__bf16)__int_as_float(__float_as_int(pb) & sb);                  \
            }                                                                              \
            int ph0 = (((lg >> 1)) + rotP) & 3;                                            \
            int ph1 = ((2 + (lg >> 1)) + rotP) & 3;                                        \
            *(bf16x4*)(pbase + lc * 64 + ph0 * 16 + (lg & 1) * 8) = pk0;                   \
            *(bf16x4*)(pbase + lc * 64 + ph1 * 16 + (lg & 1) * 8) = pk1;                   \
        }                                                                                  \
        const char* Vb = (const char*)&Vt[C][0];                                           \
        bf16x8 pf = *(const bf16x8*)(pbase + (lc * 64 + (((lg + rotP) & 3) * 16)));        \
        l_acc = __builtin_amdgcn_mfma_f32_16x16x32_bf16(pf, onesf, l_acc, 0, 0, 0);        \
        _Pragma("unroll")                                                                  \
        for (int dt = 0; dt < 4; ++dt) {                                                   \
            int row = dt * 16 + lc;                                                        \
            bf16x8 vf = *(const bf16x8*)(Vb + (row * 64 + (((lg + rotP) & 3) * 16)));      \
            if (dt == 0) o0 = __builtin_amdgcn_mfma_f32_16x16x32_bf16(pf, vf, o0, 0, 0, 0);\
            if (dt == 1) o1 = __builtin_amdgcn_mfma_f32_16x16x32_bf16(pf, vf, o1, 0, 0, 0);\
            if (dt == 2) o2 = __builtin_amdgcn_mfma_f32_16x16x32_bf16(pf, vf, o2, 0, 0, 0);\
            if (dt == 3) o3 = __builtin_amdgcn_mfma_f32_16x16x32_bf16(pf, vf, o3, 0, 0, 0);\
        }                                                                                  \
    }

    for (int s = 0; s < nsteps; s += 4) {
        ATTN_STEP(s + 0, 0, 2)
        ATTN_STEP(s + 1, 1, 3)
        ATTN_STEP(s + 2, 2, 0)
        ATTN_STEP(s + 3, 3, 1)
    }
#undef ATTN_STEP
#undef STAGE

    if (opart) {
        if (lc == 0) {
#pragma unroll
            for (int r = 0; r < 4; ++r)
                stats[(size_t)sp * 32768 + (size_t)(q0 + lg * 4 + r) * 8 + h] = l_acc[r];
        }
#pragma unroll
        for (int r = 0; r < 4; ++r) {
            size_t rh = (size_t)sp * 32768 + (size_t)(q0 + lg * 4 + r) * 8 + h;
            float* dst = opart + rh * 64;
            dst[0 * 16 + lc] = o0[r];
            dst[1 * 16 + lc] = o1[r];
            dst[2 * 16 + lc] = o2[r];
            dst[3 * 16 + lc] = o3[r];
        }
    } else {
#pragma unroll
        for (int r = 0; r < 4; ++r) {
            float inv = 1.0f / l_acc[r];
            int row = q0 + lg * 4 + r;
            __bf16* dst = ao + (size_t)row * 512 + h * 64;
            dst[0 * 16 + lc] = (__bf16)(o0[r] * inv);
            dst[1 * 16 + lc] = (__bf16)(o1[r] * inv);
            dst[2 * 16 + lc] = (__bf16)(o2[r] * inv);
            dst[3 * 16 + lc] = (__bf16)(o3[r] * inv);
        }
    }
}

// ---------------- split-KV combine (no-max softmax: plain sums) ----------------
__global__ __launch_bounds__(256) void combine_kernel(const float* __restrict__ opart,
                                                      const float* __restrict__ stats,
                                                      __bf16* __restrict__ ao, int nsplit) {
    int t = threadIdx.x, lane = t & 63, w = t >> 6;
    int rh = blockIdx.x * 4 + w;     // row*8 + h
    float L = 0.f, acc = 0.f;
#pragma unroll 2
    for (int sp = 0; sp < nsplit; ++sp) {
        L += stats[(size_t)sp * 32768 + rh];
        acc += opart[((size_t)sp * 32768 + rh) * 64 + lane];
    }
    int row = rh >> 3, h = rh & 7;
    ao[(size_t)row * 512 + h * 64 + lane] = (__bf16)(acc / L);
}

// ---------------- final FC: out[s][n] = sum_k ao[s][k] * Wfc[n][k] + bfc[n] ----------------
__global__ __launch_bounds__(256) void fc_kernel(const __bf16* __restrict__ ao,
                                                 const __bf16* __restrict__ Wb,
                                                 const float* __restrict__ bfc,
                                                 float* __restrict__ out) {
    int bid = blockIdx.x;
    int stile = bid >> 3, nt = bid & 7;
    int t = threadIdx.x, wave = t >> 6, lane = t & 63, lg = lane >> 4, lc = lane & 15;
    int s0 = stile * 64 + wave * 16;
    int n0 = nt * 64;
    f32x4 c0 = {0,0,0,0}, c1 = {0,0,0,0}, c2 = {0,0,0,0}, c3 = {0,0,0,0};
    for (int k0 = 0; k0 < 512; k0 += 32) {
        bf16x8 af = *(const bf16x8*)(ao + (size_t)(s0 + lc) * 512 + k0 + lg * 8);
        const __bf16* wb = Wb + k0 + lg * 8;
        c0 = __builtin_amdgcn_mfma_f32_16x16x32_bf16(af, *(const bf16x8*)(wb + (size_t)(n0 + 0 * 16 + lc) * 512), c0, 0, 0, 0);
        c1 = __builtin_amdgcn_mfma_f32_16x16x32_bf16(af, *(const bf16x8*)(wb + (size_t)(n0 + 1 * 16 + lc) * 512), c1, 0, 0, 0);
        c2 = __builtin_amdgcn_mfma_f32_16x16x32_bf16(af, *(const bf16x8*)(wb + (size_t)(n0 + 2 * 16 + lc) * 512), c2, 0, 0, 0);
        c3 = __builtin_amdgcn_mfma_f32_16x16x32_bf16(af, *(const bf16x8*)(wb + (size_t)(n0 + 3 * 16 + lc) * 512), c3, 0, 0, 0);
    }
#pragma unroll
    for (int r = 0; r < 4; ++r) {
        int row = s0 + lg * 4 + r;
        float* dst = out + (size_t)row * 512 + n0;
        dst[0 * 16 + lc] = c0[r] + bfc[n0 + 0 * 16 + lc];
        dst[1 * 16 + lc] = c1[r] + bfc[n0 + 1 * 16 + lc];
        dst[2 * 16 + lc] = c2[r] + bfc[n0 + 2 * 16 + lc];
        dst[3 * 16 + lc] = c3[r] + bfc[n0 + 3 * 16 + lc];
    }
}

extern "C" void kernel_launch(void* const* d_in, const int* in_sizes, int n_in,
                              void* d_out, int out_size, void* d_ws, size_t ws_size,
                              hipStream_t stream) {
    const float* query = (const float*)d_in[0];
    const float* key   = (const float*)d_in[1];
    const float* value = (const float*)d_in[2];
    const int*   mask  = (const int*)d_in[3];
    const float* Wq  = (const float*)d_in[4];
    const float* bq  = (const float*)d_in[5];
    const float* Wk  = (const float*)d_in[6];
    const float* bk  = (const float*)d_in[7];
    const float* Wv  = (const float*)d_in[8];
    const float* bv  = (const float*)d_in[9];
    const float* Wfc = (const float*)d_in[10];
    const float* bfc = (const float*)d_in[11];

    char* ws = (char*)d_ws;
    const size_t MB = 1024 * 1024;
    __bf16* q_bf   = (__bf16*)(ws + 0 * MB);      // 4 MB  [S*H][64]
    __bf16* k_bf   = (__bf16*)(ws + 4 * MB);      // 4 MB  [S*H][64]
    __bf16* vt     = (__bf16*)(ws + 8 * MB);      // 4 MB  [H][64][S]
    __bf16* ao     = (__bf16*)(ws + 12 * MB);     // 4 MB  [S][512]
    __bf16* wfc_bf = (__bf16*)(ws + 16 * MB);     // 0.5 MB
    unsigned int* mpack = (unsigned int*)(ws + 17 * MB);  // 2 MB [S][128]
    const size_t base = 19 * MB;
    int nsplit = (ws_size >= base + 2 * (8 * MB) + 2 * 131072) ? 2 : 1;
    float* opart = (float*)(ws + base);
    float* stats = (float*)(ws + base + (size_t)nsplit * 8 * MB);

    proj_all_kernel<<<1024, 256, 0, stream>>>(query, key, value, Wq, bq, Wk, bk, Wv, bv,
                                              q_bf, k_bf, vt);
    prep_kernel<<<2080, 256, 0, stream>>>(mask, mpack, Wfc, wfc_bf);
    if (nsplit > 1) {
        attn_kernel<<<512 * nsplit, 256, 0, stream>>>(q_bf, k_bf, vt, mpack,
                                                      S_LEN / nsplit / 32, opart, stats, ao);
        combine_kernel<<<8192, 256, 0, stream>>>(opart, stats, ao, nsplit);
    } else {
        attn_kernel<<<512, 256, 0, stream>>>(q_bf, k_bf, vt, mpack,
                                             128, nullptr, nullptr, ao);
    }
    fc_kernel<<<512, 256, 0, stream>>>(ao, wfc_bf, bfc, (float*)d_out);
}

// Round 13
// 119.606 us; speedup vs baseline: 1.8801x; 1.0332x over previous
//
#include <hip/hip_runtime.h>
#include <hip/hip_bf16.h>

#define S_LEN 4096
#define DMODEL 512
#define NHEAD 8
#define HDIM 64

typedef __bf16 bf16x8 __attribute__((ext_vector_type(8)));
typedef __bf16 bf16x4 __attribute__((ext_vector_type(4)));
typedef float f32x4 __attribute__((ext_vector_type(4)));

#define S2EXP 0.18033688011112042f   // 0.125 * log2(e), folded into Q projection

__device__ __forceinline__ void gload_lds16(const void* g, void* l) {
    __builtin_amdgcn_global_load_lds((const __attribute__((address_space(1))) void*)g,
                                     (__attribute__((address_space(3))) void*)l, 16, 0, 0);
}
__device__ __forceinline__ void gload_lds4(const void* g, void* l) {
    __builtin_amdgcn_global_load_lds((const __attribute__((address_space(1))) void*)g,
                                     (__attribute__((address_space(3))) void*)l, 4, 0, 0);
}

// ---------------- fused projections: blocks 0-511 q+k, 512-1023 v(+transpose) ----------------
__global__ __launch_bounds__(256) void proj_all_kernel(const float* __restrict__ xq,
                                                       const float* __restrict__ xk,
                                                       const float* __restrict__ xv,
                                                       const float* __restrict__ Wq,
                                                       const float* __restrict__ bq,
                                                       const float* __restrict__ Wk,
                                                       const float* __restrict__ bk,
                                                       const float* __restrict__ Wv,
                                                       const float* __restrict__ bv,
                                                       __bf16* __restrict__ yq,
                                                       __bf16* __restrict__ yk,
                                                       __bf16* __restrict__ vt) {
    __shared__ float T[64][65];
    int bid = blockIdx.x;
    int t = threadIdx.x, wave = t >> 6, lane = t & 63, lg = lane >> 4, lc = lane & 15;
    if (bid < 512) {
        int r0 = bid * 64 + wave * 16;
        const float* xrq = xq + (size_t)(r0 + lc) * 64 + lg * 8;
        const float* xrk = xk + (size_t)(r0 + lc) * 64 + lg * 8;
        bf16x8 aq[2], ak[2];
#pragma unroll
        for (int c = 0; c < 2; ++c) {
            f32x4 u0 = *(const f32x4*)(xrq + c * 32);
            f32x4 u1 = *(const f32x4*)(xrq + c * 32 + 4);
            f32x4 v0 = *(const f32x4*)(xrk + c * 32);
            f32x4 v1 = *(const f32x4*)(xrk + c * 32 + 4);
            bf16x8 a, b;
#pragma unroll
            for (int j = 0; j < 4; ++j) {
                a[j] = (__bf16)u0[j]; a[4 + j] = (__bf16)u1[j];
                b[j] = (__bf16)v0[j]; b[4 + j] = (__bf16)v1[j];
            }
            aq[c] = a; ak[c] = b;
        }
#pragma unroll
        for (int nt = 0; nt < 4; ++nt) {
            const float* wq = Wq + (size_t)(nt * 16 + lc) * 64 + lg * 8;
            const float* wk = Wk + (size_t)(nt * 16 + lc) * 64 + lg * 8;
            f32x4 cq = {0, 0, 0, 0}, ck = {0, 0, 0, 0};
#pragma unroll
            for (int c = 0; c < 2; ++c) {
                f32x4 u0 = *(const f32x4*)(wq + c * 32);
                f32x4 u1 = *(const f32x4*)(wq + c * 32 + 4);
                f32x4 v0 = *(const f32x4*)(wk + c * 32);
                f32x4 v1 = *(const f32x4*)(wk + c * 32 + 4);
                bf16x8 bw, bw2;
#pragma unroll
                for (int j = 0; j < 4; ++j) {
                    bw[j] = (__bf16)u0[j]; bw[4 + j] = (__bf16)u1[j];
                    bw2[j] = (__bf16)v0[j]; bw2[4 + j] = (__bf16)v1[j];
                }
                cq = __builtin_amdgcn_mfma_f32_16x16x32_bf16(aq[c], bw, cq, 0, 0, 0);
                ck = __builtin_amdgcn_mfma_f32_16x16x32_bf16(ak[c], bw2, ck, 0, 0, 0);
            }
            float bqv = bq[nt * 16 + lc], bkv = bk[nt * 16 + lc];
#pragma unroll
            for (int r = 0; r < 4; ++r) {
                yq[(size_t)(r0 + lg * 4 + r) * 64 + nt * 16 + lc] = (__bf16)((cq[r] + bqv) * S2EXP);
                yk[(size_t)(r0 + lg * 4 + r) * 64 + nt * 16 + lc] = (__bf16)(ck[r] + bkv);
            }
        }
    } else {
        int vb = bid - 512;
        int h = vb & 7, s0 = (vb >> 3) * 64;
        const float* xr = xv + ((size_t)(s0 + wave * 16 + lc) * 8 + h) * 64 + lg * 8;
        bf16x8 av[2];
#pragma unroll
        for (int c = 0; c < 2; ++c) {
            f32x4 u0 = *(const f32x4*)(xr + c * 32);
            f32x4 u1 = *(const f32x4*)(xr + c * 32 + 4);
            bf16x8 a;
#pragma unroll
            for (int j = 0; j < 4; ++j) { a[j] = (__bf16)u0[j]; a[4 + j] = (__bf16)u1[j]; }
            av[c] = a;
        }
#pragma unroll
        for (int nt = 0; nt < 4; ++nt) {
            const float* wv = Wv + (size_t)(nt * 16 + lc) * 64 + lg * 8;
            f32x4 cv = {0, 0, 0, 0};
#pragma unroll
            for (int c = 0; c < 2; ++c) {
                f32x4 u0 = *(const f32x4*)(wv + c * 32);
                f32x4 u1 = *(const f32x4*)(wv + c * 32 + 4);
                bf16x8 bw;
#pragma unroll
                for (int j = 0; j < 4; ++j) { bw[j] = (__bf16)u0[j]; bw[4 + j] = (__bf16)u1[j]; }
                cv = __builtin_amdgcn_mfma_f32_16x16x32_bf16(av[c], bw, cv, 0, 0, 0);
            }
            float bvv = bv[nt * 16 + lc];
#pragma unroll
            for (int r = 0; r < 4; ++r) T[wave * 16 + lg * 4 + r][nt * 16 + lc] = cv[r] + bvv;
        }
        __syncthreads();
        int d = t >> 2, qr = t & 3;
        bf16x8 w0, w1;
#pragma unroll
        for (int i = 0; i < 8; ++i) {
            w0[i] = (__bf16)T[qr * 16 + i][d];
            w1[i] = (__bf16)T[qr * 16 + 8 + i][d];
        }
        __bf16* dst = vt + ((size_t)h * 64 + d) * 4096 + s0 + qr * 16;
        *(bf16x8*)(dst) = w0;
        *(bf16x8*)(dst + 8) = w1;
    }
}

// ---------------- prep: blocks 0-2047 mask packing, 2048-2079 Wfc f32->bf16 ----------------
__global__ __launch_bounds__(256) void prep_kernel(const int* __restrict__ mask,
                                                   unsigned int* __restrict__ pack,
                                                   const float* __restrict__ Wfc,
                                                   __bf16* __restrict__ wfc_bf) {
    int bid = blockIdx.x;
    int t = threadIdx.x;
    if (bid < 2048) {
        int lane = t & 63;
        int wid = bid * 4 + (t >> 6);
#pragma unroll 4
        for (int it = 0; it < 32; ++it) {
            int gw = wid * 32 + it;
            int qi = gw >> 6, seg = gw & 63;
            unsigned long long bits = __ballot(mask[(size_t)qi * 4096 + seg * 64 + lane] != 0);
            if (lane == 0)
                *(unsigned long long*)(&pack[(size_t)qi * 128 + seg * 2]) = bits;
        }
    } else {
        int b = bid - 2048;
        const f32x4* s4 = (const f32x4*)Wfc;
#pragma unroll
        for (int i = 0; i < 8; ++i) {
            int idx = (b * 8 + i) * 256 + t;     // f32x4 index, 65536 total
            f32x4 v = s4[idx];
            bf16x4 o;
#pragma unroll
            for (int j = 0; j < 4; ++j) o[j] = (__bf16)v[j];
            *(bf16x4*)(wfc_bf + (size_t)idx * 4) = o;
        }
    }
}

// ---------------- flash attention: 32 q/wave, 4-buffer counted-vmcnt, KV-step 32 ----------------
// block: h = bid&7 (head -> XCD), qtb = (bid>>3)&31 (128 q-rows), sp = bid>>8 (3 splits)
// Each wave owns 32 q-rows (2 q-tiles) -> K/V LDS reads per output element halved vs 16 q/wave.
// Ring: stage tile s+2 -> vmcnt(4) -> s_barrier -> compute s. Dummy clamped stage keeps the
// vmcnt invariant on the last 2 steps (fixes last-tile race).
__global__ __launch_bounds__(256, 3) void attn_kernel(const __bf16* __restrict__ qb,
                                                      const __bf16* __restrict__ kb,
                                                      const __bf16* __restrict__ vt,
                                                      const unsigned int* __restrict__ mp,
                                                      int split_steps,
                                                      float* __restrict__ opart,
                                                      float* __restrict__ stats,
                                                      __bf16* __restrict__ ao) {
    int bid = blockIdx.x;
    int h = bid & 7, qtb = (bid >> 3) & 31, sp = bid >> 8;
    int kv0 = sp * split_steps * 32;
    int nsteps = min(split_steps, 128 - sp * split_steps);
    int t = threadIdx.x, wave = t >> 6, lane = t & 63, lg = lane >> 4, lc = lane & 15;
    int q0 = qtb * 128 + wave * 32;

    __shared__ __bf16 Kt[4][32 * 64];        // 16KB: k-rows, 128B, XOR swz ((row&7)<<4)
    __shared__ __bf16 Vt[4][64 * 32];        // 16KB: d-rows, 64B, chunk-rotation swz
    __shared__ __bf16 P[4][32 * 32];         // 8KB: per-wave 32q x 32k, chunk-rotation swz
    __shared__ unsigned int Mld[4][128];     // 2KB: mask word per q-row per buffered tile

    int srK = lane >> 3;
    int cgK = (lane & 7) ^ srK;                      // inverse XOR swizzle (K)
    int srV = lane >> 2;
    int cgV = ((lane & 3) - ((lane >> 3) & 3)) & 3;  // inverse rotation (V)

    const __bf16* qr0 = qb + ((size_t)(q0 + lc) * 8 + h) * 64 + lg * 8;
    const __bf16* qr1 = qb + ((size_t)(q0 + 16 + lc) * 8 + h) * 64 + lg * 8;
    bf16x8 qf00 = *(const bf16x8*)(qr0);
    bf16x8 qf01 = *(const bf16x8*)(qr0 + 32);
    bf16x8 qf10 = *(const bf16x8*)(qr1);
    bf16x8 qf11 = *(const bf16x8*)(qr1 + 32);

    bf16x8 onesf;
#pragma unroll
    for (int j = 0; j < 8; ++j) onesf[j] = (__bf16)1.0f;

    f32x4 o00 = {0,0,0,0}, o01 = {0,0,0,0}, o02 = {0,0,0,0}, o03 = {0,0,0,0};
    f32x4 o10 = {0,0,0,0}, o11 = {0,0,0,0}, o12 = {0,0,0,0}, o13 = {0,0,0,0};
    f32x4 lac0 = {0,0,0,0}, lac1 = {0,0,0,0};

    const __bf16* vbase = vt + (size_t)h * 64 * 4096;
    // mask source: lane l of wave w (<2) stages q-row qtb*128 + w*64 + l
    const unsigned int* mbase = mp + (size_t)(qtb * 128 + wave * 64 + lane) * 128 + (kv0 >> 5);

    int rotP = (lc >> 1) & 3;
    int lg4 = lg * 4;

#define STAGE(tt, B)                                                                          \
    {                                                                                         \
        if (wave < 2) gload_lds4(mbase + (tt), &Mld[B][wave * 64]);                           \
        gload_lds16(kb + (size_t)(kv0 + (tt) * 32 + wave * 8 + srK) * 512 + h * 64 + cgK * 8, \
                    &Kt[B][wave * 512]);                                                      \
        gload_lds16(vbase + (size_t)(wave * 16 + srV) * 4096 + kv0 + (tt) * 32 + cgV * 8,     \
                    &Vt[B][wave * 512]);                                                      \
    }

    // ---- prologue: stage tiles 0,1; full drain once ----
    STAGE(0, 0)
    STAGE(1, 1)
    asm volatile("s_waitcnt vmcnt(0)" ::: "memory");
    __builtin_amdgcn_s_barrier();

#define ATTN_STEP(s, C, G)                                                                    \
    {                                                                                         \
        STAGE(min((s) + 2, nsteps - 1), G)                                                    \
        asm volatile("s_waitcnt vmcnt(4)" ::: "memory");                                      \
        __builtin_amdgcn_s_barrier();                                                         \
        unsigned int mw0 = Mld[C][wave * 32 + lc] >> lg4;                                     \
        unsigned int mw1 = Mld[C][wave * 32 + 16 + lc] >> lg4;                                \
        const char* Kb = (const char*)&Kt[C][0];                                              \
        f32x4 s00 = {0,0,0,0}, s01 = {0,0,0,0}, s10 = {0,0,0,0}, s11 = {0,0,0,0};             \
        {                                                                                     \
            int row = lc, sw = (row & 7) << 4;                                                \
            bf16x8 ka = *(const bf16x8*)(Kb + ((row * 128 + lg * 16) ^ sw));                  \
            bf16x8 kc_ = *(const bf16x8*)(Kb + ((row * 128 + 64 + lg * 16) ^ sw));            \
            s00 = __builtin_amdgcn_mfma_f32_16x16x32_bf16(ka, qf00, s00, 0, 0, 0);            \
            s00 = __builtin_amdgcn_mfma_f32_16x16x32_bf16(kc_, qf01, s00, 0, 0, 0);           \
            s01 = __builtin_amdgcn_mfma_f32_16x16x32_bf16(ka, qf10, s01, 0, 0, 0);            \
            s01 = __builtin_amdgcn_mfma_f32_16x16x32_bf16(kc_, qf11, s01, 0, 0, 0);           \
        }                                                                                     \
        {                                                                                     \
            int row = 16 + lc, sw = (row & 7) << 4;                                           \
            bf16x8 ka = *(const bf16x8*)(Kb + ((row * 128 + lg * 16) ^ sw));                  \
            bf16x8 kc_ = *(const bf16x8*)(Kb + ((row * 128 + 64 + lg * 16) ^ sw));            \
            s10 = __builtin_amdgcn_mfma_f32_16x16x32_bf16(ka, qf00, s10, 0, 0, 0);            \
            s10 = __builtin_amdgcn_mfma_f32_16x16x32_bf16(kc_, qf01, s10, 0, 0, 0);           \
            s11 = __builtin_amdgcn_mfma_f32_16x16x32_bf16(ka, qf10, s11, 0, 0, 0);            \
            s11 = __builtin_amdgcn_mfma_f32_16x16x32_bf16(kc_, qf11, s11, 0, 0, 0);           \
        }                                                                                     \
        char* pb = (char*)&P[wave][0];                                                        \
        {                                                                                     \
            bf16x4 k0q0, k1q0, k0q1, k1q1;                                                    \
            _Pragma("unroll")                                                                 \
            for (int r = 0; r < 4; ++r) {                                                     \
                float pa = __builtin_amdgcn_exp2f(s00[r]);                                    \
                k0q0[r] = (__bf16)__int_as_float(__float_as_int(pa) &                         \
                                                 __builtin_amdgcn_sbfe((int)mw0, r, 1));      \
                float pc = __builtin_amdgcn_exp2f(s10[r]);                                    \
                k1q0[r] = (__bf16)__int_as_float(__float_as_int(pc) &                         \
                                                 __builtin_amdgcn_sbfe((int)mw0, 16 + r, 1)); \
                float pd = __builtin_amdgcn_exp2f(s01[r]);                                    \
                k0q1[r] = (__bf16)__int_as_float(__float_as_int(pd) &                         \
                                                 __builtin_amdgcn_sbfe((int)mw1, r, 1));      \
                float pe = __builtin_amdgcn_exp2f(s11[r]);                                    \
                k1q1[r] = (__bf16)__int_as_float(__float_as_int(pe) &                         \
                                                 __builtin_amdgcn_sbfe((int)mw1, 16 + r, 1)); \
            }                                                                                 \
            int ph0 = ((lg >> 1) + rotP) & 3;                                                 \
            int ph1 = (2 + (lg >> 1) + rotP) & 3;                                             \
            int ib = (lg & 1) * 8;                                                            \
            *(bf16x4*)(pb + lc * 64 + ph0 * 16 + ib) = k0q0;                                  \
            *(bf16x4*)(pb + lc * 64 + ph1 * 16 + ib) = k1q0;                                  \
            *(bf16x4*)(pb + 1024 + lc * 64 + ph0 * 16 + ib) = k0q1;                           \
            *(bf16x4*)(pb + 1024 + lc * 64 + ph1 * 16 + ib) = k1q1;                           \
        }                                                                                     \
        int prd = lc * 64 + (((lg + rotP) & 3) * 16);                                         \
        bf16x8 pf0 = *(const bf16x8*)(pb + prd);                                              \
        bf16x8 pf1 = *(const bf16x8*)(pb + 1024 + prd);                                       \
        lac0 = __builtin_amdgcn_mfma_f32_16x16x32_bf16(pf0, onesf, lac0, 0, 0, 0);            \
        lac1 = __builtin_amdgcn_mfma_f32_16x16x32_bf16(pf1, onesf, lac1, 0, 0, 0);            \
        const char* Vb = (const char*)&Vt[C][0];                                              \
        {                                                                                     \
            bf16x8 vf = *(const bf16x8*)(Vb + ((0 * 16 + lc) * 64 + (((lg + rotP) & 3) * 16)));\
            o00 = __builtin_amdgcn_mfma_f32_16x16x32_bf16(pf0, vf, o00, 0, 0, 0);             \
            o10 = __builtin_amdgcn_mfma_f32_16x16x32_bf16(pf1, vf, o10, 0, 0, 0);             \
        }                                                                                     \
        {                                                                                     \
            bf16x8 vf = *(const bf16x8*)(Vb + ((1 * 16 + lc) * 64 + (((lg + rotP) & 3) * 16)));\
            o01 = __builtin_amdgcn_mfma_f32_16x16x32_bf16(pf0, vf, o01, 0, 0, 0);             \
            o11 = __builtin_amdgcn_mfma_f32_16x16x32_bf16(pf1, vf, o11, 0, 0, 0);             \
        }                                                                                     \
        {                                                                                     \
            bf16x8 vf = *(const bf16x8*)(Vb + ((2 * 16 + lc) * 64 + (((lg + rotP) & 3) * 16)));\
            o02 = __builtin_amdgcn_mfma_f32_16x16x32_bf16(pf0, vf, o02, 0, 0, 0);             \
            o12 = __builtin_amdgcn_mfma_f32_16x16x32_bf16(pf1, vf, o12, 0, 0, 0);             \
        }                                                                                     \
        {                                                                                     \
            bf16x8 vf = *(const bf16x8*)(Vb + ((3 * 16 + lc) * 64 + (((lg + rotP) & 3) * 16)));\
            o03 = __builtin_amdgcn_mfma_f32_16x16x32_bf16(pf0, vf, o03, 0, 0, 0);             \
            o13 = __builtin_amdgcn_mfma_f32_16x16x32_bf16(pf1, vf, o13, 0, 0, 0);             \
        }                                                                                     \
    }

    int s = 0;
    for (; s + 4 <= nsteps; s += 4) {
        ATTN_STEP(s + 0, 0, 2)
        ATTN_STEP(s + 1, 1, 3)
        ATTN_STEP(s + 2, 2, 0)
        ATTN_STEP(s + 3, 3, 1)
    }
    if (s < nsteps) { ATTN_STEP(s, 0, 2) s++; }
    if (s < nsteps) { ATTN_STEP(s, 1, 3) s++; }
    if (s < nsteps) { ATTN_STEP(s, 2, 0) s++; }
#undef ATTN_STEP
#undef STAGE

    // ---- epilogue: 2 q-tiles per wave ----
    if (opart) {
        if (lc == 0) {
#pragma unroll
            for (int r = 0; r < 4; ++r) {
                stats[(size_t)sp * 32768 + (size_t)(q0 + lg * 4 + r) * 8 + h]      = lac0[r];
                stats[(size_t)sp * 32768 + (size_t)(q0 + 16 + lg * 4 + r) * 8 + h] = lac1[r];
            }
        }
#pragma unroll
        for (int r = 0; r < 4; ++r) {
            size_t rh0 = (size_t)sp * 32768 + (size_t)(q0 + lg * 4 + r) * 8 + h;
            float* d0 = opart + rh0 * 64;
            d0[0 * 16 + lc] = o00[r]; d0[1 * 16 + lc] = o01[r];
            d0[2 * 16 + lc] = o02[r]; d0[3 * 16 + lc] = o03[r];
            size_t rh1 = (size_t)sp * 32768 + (size_t)(q0 + 16 + lg * 4 + r) * 8 + h;
            float* d1 = opart + rh1 * 64;
            d1[0 * 16 + lc] = o10[r]; d1[1 * 16 + lc] = o11[r];
            d1[2 * 16 + lc] = o12[r]; d1[3 * 16 + lc] = o13[r];
        }
    } else {
#pragma unroll
        for (int r = 0; r < 4; ++r) {
            float inv0 = 1.0f / lac0[r];
            __bf16* d0 = ao + (size_t)(q0 + lg * 4 + r) * 512 + h * 64;
            d0[0 * 16 + lc] = (__bf16)(o00[r] * inv0); d0[1 * 16 + lc] = (__bf16)(o01[r] * inv0);
            d0[2 * 16 + lc] = (__bf16)(o02[r] * inv0); d0[3 * 16 + lc] = (__bf16)(o03[r] * inv0);
            float inv1 = 1.0f / lac1[r];
            __bf16* d1 = ao + (size_t)(q0 + 16 + lg * 4 + r) * 512 + h * 64;
            d1[0 * 16 + lc] = (__bf16)(o10[r] * inv1); d1[1 * 16 + lc] = (__bf16)(o11[r] * inv1);
            d1[2 * 16 + lc] = (__bf16)(o12[r] * inv1); d1[3 * 16 + lc] = (__bf16)(o13[r] * inv1);
        }
    }
}

// ---------------- split-KV combine (no-max softmax: plain sums) ----------------
__global__ __launch_bounds__(256) void combine_kernel(const float* __restrict__ opart,
                                                      const float* __restrict__ stats,
                                                      __bf16* __restrict__ ao, int nsplit) {
    int t = threadIdx.x, lane = t & 63, w = t >> 6;
    int rh = blockIdx.x * 4 + w;     // row*8 + h
    float L = 0.f, acc = 0.f;
#pragma unroll 3
    for (int sp = 0; sp < nsplit; ++sp) {
        L += stats[(size_t)sp * 32768 + rh];
        acc += opart[((size_t)sp * 32768 + rh) * 64 + lane];
    }
    int row = rh >> 3, h = rh & 7;
    ao[(size_t)row * 512 + h * 64 + lane] = (__bf16)(acc / L);
}

// ---------------- final FC: out[s][n] = sum_k ao[s][k] * Wfc[n][k] + bfc[n] ----------------
__global__ __launch_bounds__(256) void fc_kernel(const __bf16* __restrict__ ao,
                                                 const __bf16* __restrict__ Wb,
                                                 const float* __restrict__ bfc,
                                                 float* __restrict__ out) {
    int bid = blockIdx.x;
    int stile = bid >> 3, nt = bid & 7;
    int t = threadIdx.x, wave = t >> 6, lane = t & 63, lg = lane >> 4, lc = lane & 15;
    int s0 = stile * 64 + wave * 16;
    int n0 = nt * 64;
    f32x4 c0 = {0,0,0,0}, c1 = {0,0,0,0}, c2 = {0,0,0,0}, c3 = {0,0,0,0};
    for (int k0 = 0; k0 < 512; k0 += 32) {
        bf16x8 af = *(const bf16x8*)(ao + (size_t)(s0 + lc) * 512 + k0 + lg * 8);
        const __bf16* wb = Wb + k0 + lg * 8;
        c0 = __builtin_amdgcn_mfma_f32_16x16x32_bf16(af, *(const bf16x8*)(wb + (size_t)(n0 + 0 * 16 + lc) * 512), c0, 0, 0, 0);
        c1 = __builtin_amdgcn_mfma_f32_16x16x32_bf16(af, *(const bf16x8*)(wb + (size_t)(n0 + 1 * 16 + lc) * 512), c1, 0, 0, 0);
        c2 = __builtin_amdgcn_mfma_f32_16x16x32_bf16(af, *(const bf16x8*)(wb + (size_t)(n0 + 2 * 16 + lc) * 512), c2, 0, 0, 0);
        c3 = __builtin_amdgcn_mfma_f32_16x16x32_bf16(af, *(const bf16x8*)(wb + (size_t)(n0 + 3 * 16 + lc) * 512), c3, 0, 0, 0);
    }
#pragma unroll
    for (int r = 0; r < 4; ++r) {
        int row = s0 + lg * 4 + r;
        float* dst = out + (size_t)row * 512 + n0;
        dst[0 * 16 + lc] = c0[r] + bfc[n0 + 0 * 16 + lc];
        dst[1 * 16 + lc] = c1[r] + bfc[n0 + 1 * 16 + lc];
        dst[2 * 16 + lc] = c2[r] + bfc[n0 + 2 * 16 + lc];
        dst[3 * 16 + lc] = c3[r] + bfc[n0 + 3 * 16 + lc];
    }
}

extern "C" void kernel_launch(void* const* d_in, const int* in_sizes, int n_in,
                              void* d_out, int out_size, void* d_ws, size_t ws_size,
                              hipStream_t stream) {
    const float* query = (const float*)d_in[0];
    const float* key   = (const float*)d_in[1];
    const float* value = (const float*)d_in[2];
    const int*   mask  = (const int*)d_in[3];
    const float* Wq  = (const float*)d_in[4];
    const float* bq  = (const float*)d_in[5];
    const float* Wk  = (const float*)d_in[6];
    const float* bk  = (const float*)d_in[7];
    const float* Wv  = (const float*)d_in[8];
    const float* bv  = (const float*)d_in[9];
    const float* Wfc = (const float*)d_in[10];
    const float* bfc = (const float*)d_in[11];

    char* ws = (char*)d_ws;
    const size_t MB = 1024 * 1024;
    __bf16* q_bf   = (__bf16*)(ws + 0 * MB);      // 4 MB  [S*H][64]
    __bf16* k_bf   = (__bf16*)(ws + 4 * MB);      // 4 MB  [S*H][64]
    __bf16* vt     = (__bf16*)(ws + 8 * MB);      // 4 MB  [H][64][S]
    __bf16* ao     = (__bf16*)(ws + 12 * MB);     // 4 MB  [S][512]
    __bf16* wfc_bf = (__bf16*)(ws + 16 * MB);     // 0.5 MB
    unsigned int* mpack = (unsigned int*)(ws + 17 * MB);  // 2 MB [S][128]
    const size_t base = 19 * MB;
    int nsplit = (ws_size >= base + 3 * (8 * MB) + 3 * 131072) ? 3 : 1;
    float* opart = (float*)(ws + base);
    float* stats = (float*)(ws + base + (size_t)nsplit * 8 * MB);

    proj_all_kernel<<<1024, 256, 0, stream>>>(query, key, value, Wq, bq, Wk, bk, Wv, bv,
                                              q_bf, k_bf, vt);
    prep_kernel<<<2080, 256, 0, stream>>>(mask, mpack, Wfc, wfc_bf);
    if (nsplit > 1) {
        // 3 splits of 43/43/42 steps; grid = 32 qtb x 8 h x 3 = 768 = 3 blocks/CU exactly
        attn_kernel<<<256 * nsplit, 256, 0, stream>>>(q_bf, k_bf, vt, mpack,
                                                      43, opart, stats, ao);
        combine_kernel<<<8192, 256, 0, stream>>>(opart, stats, ao, nsplit);
    } else {
        attn_kernel<<<256, 256, 0, stream>>>(q_bf, k_bf, vt, mpack,
                                             128, nullptr, nullptr, ao);
    }
    fc_kernel<<<512, 256, 0, stream>>>(ao, wfc_bf, bfc, (float*)d_out);
}